// Round 1
// baseline (34.170 us; speedup 1.0000x reference)
//
#include <hip/hip_runtime.h>
#include <math.h>

// Problem constants (from reference setup): B=4, N=65536, M=128.
#define NPTS 65536
#define MBOX 128

// Prep: per-box derived data {cx,cy,cz,hx,hy,hz,cos,sin} -> d_ws.
// Accurate sinf/cosf (~1 ulp) to match numpy float32 reference.
__global__ __launch_bounds__(256) void prep_boxes(const float* __restrict__ boxes,
                                                  float* __restrict__ prep,
                                                  int total) {
    int i = blockIdx.x * 256 + threadIdx.x;
    if (i >= total) return;
    const float* bx = boxes + (size_t)i * 7;
    float cx = bx[0], cy = bx[1], cz = bx[2];
    float hx = 0.5f * bx[3];   // *0.5 is exact, matches ref dims*0.5
    float hy = 0.5f * bx[4];
    float hz = 0.5f * bx[5];
    float rz = bx[6];
    float cr = cosf(rz);
    float sr = sinf(rz);
    float* o = prep + (size_t)i * 8;
    o[0] = cx; o[1] = cy; o[2] = cz;
    o[3] = hx; o[4] = hy; o[5] = hz;
    o[6] = cr; o[7] = sr;
}

// Main: one thread per point; loop boxes in ascending order, record first hit.
// Box reads are wave-uniform -> scalar (s_load) path; inner loop is pure VALU.
// __f*_rn intrinsics block fp-contract so rounding matches the np reference
// (mul, mul, add — no fma), minimizing boundary-flip risk.
__global__ __launch_bounds__(256) void pib_main(const float* __restrict__ points,
                                                const float* __restrict__ prep,
                                                float* __restrict__ out) {
    int b  = blockIdx.x >> 8;                    // 65536/256 = 256 blocks/batch
    int pi = ((blockIdx.x & 255) << 8) + threadIdx.x;

    const float* p = points + ((size_t)b * NPTS + pi) * 3;
    float px = p[0], py = p[1], pz = p[2];

    const float* bb = prep + (size_t)b * MBOX * 8;

    int idx = -1;
    #pragma unroll 4
    for (int m = 0; m < MBOX; ++m) {
        const float* q = bb + m * 8;
        float cx = q[0], cy = q[1], cz = q[2];
        float hx = q[3], hy = q[4], hz = q[5];
        float cr = q[6], sr = q[7];

        float lx0 = __fsub_rn(px, cx);
        float ly0 = __fsub_rn(py, cy);
        float lz  = __fsub_rn(pz, cz);
        // ref: lx = lx0*cos + ly0*sin ; ly = -lx0*sin + ly0*cos (no fma)
        float lx = __fadd_rn(__fmul_rn(lx0, cr), __fmul_rn(ly0, sr));
        float ly = __fadd_rn(__fmul_rn(-lx0, sr), __fmul_rn(ly0, cr));

        bool in = (fabsf(lx) <= hx) & (fabsf(ly) <= hy) & (fabsf(lz) <= hz);
        if (in & (idx < 0)) idx = m;   // first containing box wins
    }

    out[(size_t)b * NPTS + pi] = (float)idx;
}

extern "C" void kernel_launch(void* const* d_in, const int* in_sizes, int n_in,
                              void* d_out, int out_size, void* d_ws, size_t ws_size,
                              hipStream_t stream) {
    const float* points = (const float*)d_in[0];   // [B, N, 3] f32
    const float* boxes  = (const float*)d_in[1];   // [B, M, 7] f32
    float* out = (float*)d_out;                    // [B, N]    f32
    float* prep = (float*)d_ws;                    // [B*M, 8]  f32 = 16 KB

    int n_points = in_sizes[0] / 3;                // B*N = 262144
    int n_boxes  = in_sizes[1] / 7;                // B*M = 512
    int B = n_points / NPTS;

    int prep_blocks = (n_boxes + 255) / 256;
    prep_boxes<<<prep_blocks, 256, 0, stream>>>(boxes, prep, n_boxes);

    int main_blocks = B * (NPTS / 256);            // 1024
    pib_main<<<main_blocks, 256, 0, stream>>>(points, prep, out);
}

// Round 2
// 25.704 us; speedup vs baseline: 1.3293x; 1.3293x over previous
//
#include <hip/hip_runtime.h>
#include <math.h>

// Problem constants (from reference setup): B=4, N=65536, M=128.
#define NPTS 65536
#define MBOX 128
#define TPB  256
#define PPT  2              // points per thread (2 independent dep chains)
#define PPB  (TPB * PPT)    // 512 points per block

// Prep: per-box derived data {cx,cy,cz,hx, hy,hz,cos,sin} -> d_ws.
// Accurate sinf/cosf (~1 ulp) matches numpy f32 reference (absmax=0 in R1).
__global__ __launch_bounds__(256) void prep_boxes(const float* __restrict__ boxes,
                                                  float* __restrict__ prep,
                                                  int total) {
    int i = blockIdx.x * 256 + threadIdx.x;
    if (i >= total) return;
    const float* bx = boxes + (size_t)i * 7;
    float rz = bx[6];
    float* o = prep + (size_t)i * 8;
    o[0] = bx[0];          // cx
    o[1] = bx[1];          // cy
    o[2] = bx[2];          // cz
    o[3] = 0.5f * bx[3];   // hx (exact, matches ref dims*0.5)
    o[4] = 0.5f * bx[4];   // hy
    o[5] = 0.5f * bx[5];   // hz
    o[6] = cosf(rz);
    o[7] = sinf(rz);
}

// Main: 2 points/thread. Per-batch box table staged in LDS (4 KB); inner-loop
// reads are wave-uniform -> LDS broadcast (no VMEM, no bank conflicts).
// Descending-m overwrite: last write at smallest m == first containing box.
// __f*_rn blocks fp-contract so rounding matches np (mul, mul, add — no fma).
__global__ __launch_bounds__(256) void pib_main(const float* __restrict__ points,
                                                const float* __restrict__ prep,
                                                float* __restrict__ out) {
    __shared__ float sb[MBOX * 8];  // 4 KB

    const int blocksPerBatch = NPTS / PPB;            // 128
    int b   = blockIdx.x / blocksPerBatch;
    int blk = blockIdx.x % blocksPerBatch;

    // Stage boxes: 256 float4s, one per thread, coalesced.
    ((float4*)sb)[threadIdx.x] =
        ((const float4*)(prep + (size_t)b * MBOX * 8))[threadIdx.x];
    __syncthreads();

    size_t p0 = (size_t)b * NPTS + (size_t)blk * PPB + (size_t)threadIdx.x * PPT;
    const float* p = points + p0 * 3;                 // 24B per thread, 8B aligned
    float2 a01 = *(const float2*)(p);
    float2 a23 = *(const float2*)(p + 2);
    float2 a45 = *(const float2*)(p + 4);
    float px0 = a01.x, py0 = a01.y, pz0 = a23.x;
    float px1 = a23.y, py1 = a45.x, pz1 = a45.y;

    int idx0 = -1, idx1 = -1;
    #pragma unroll 8
    for (int m = MBOX - 1; m >= 0; --m) {
        float4 q0 = *(const float4*)(sb + m * 8);     // uniform addr -> broadcast
        float4 q1 = *(const float4*)(sb + m * 8 + 4);
        float cx = q0.x, cy = q0.y, cz = q0.z, hx = q0.w;
        float hy = q1.x, hz = q1.y, cr = q1.z, sr = q1.w;

        // point 0
        float lx0 = __fsub_rn(px0, cx);
        float ly0 = __fsub_rn(py0, cy);
        float lz0 = __fsub_rn(pz0, cz);
        float X0 = __fadd_rn(__fmul_rn(lx0, cr), __fmul_rn(ly0, sr));
        float Y0 = __fadd_rn(__fmul_rn(-lx0, sr), __fmul_rn(ly0, cr));
        bool in0 = (fabsf(X0) <= hx) & (fabsf(Y0) <= hy) & (fabsf(lz0) <= hz);
        idx0 = in0 ? m : idx0;

        // point 1
        float lx1 = __fsub_rn(px1, cx);
        float ly1 = __fsub_rn(py1, cy);
        float lz1 = __fsub_rn(pz1, cz);
        float X1 = __fadd_rn(__fmul_rn(lx1, cr), __fmul_rn(ly1, sr));
        float Y1 = __fadd_rn(__fmul_rn(-lx1, sr), __fmul_rn(ly1, cr));
        bool in1 = (fabsf(X1) <= hx) & (fabsf(Y1) <= hy) & (fabsf(lz1) <= hz);
        idx1 = in1 ? m : idx1;
    }

    // p0 is even -> 8B aligned float2 store, coalesced.
    *(float2*)(out + p0) = make_float2((float)idx0, (float)idx1);
}

extern "C" void kernel_launch(void* const* d_in, const int* in_sizes, int n_in,
                              void* d_out, int out_size, void* d_ws, size_t ws_size,
                              hipStream_t stream) {
    const float* points = (const float*)d_in[0];   // [B, N, 3] f32
    const float* boxes  = (const float*)d_in[1];   // [B, M, 7] f32
    float* out = (float*)d_out;                    // [B, N]    f32
    float* prep = (float*)d_ws;                    // [B*M, 8]  f32 = 16 KB

    int n_points = in_sizes[0] / 3;                // B*N = 262144
    int n_boxes  = in_sizes[1] / 7;                // B*M = 512

    int prep_blocks = (n_boxes + 255) / 256;
    prep_boxes<<<prep_blocks, 256, 0, stream>>>(boxes, prep, n_boxes);

    int main_blocks = n_points / PPB;              // 512
    pib_main<<<main_blocks, 256, 0, stream>>>(points, prep, out);
}

// Round 3
// 21.270 us; speedup vs baseline: 1.6065x; 1.2085x over previous
//
#include <hip/hip_runtime.h>
#include <math.h>

// Problem constants (from reference setup): B=4, N=65536, M=128.
#define NPTS 65536
#define MBOX 128
#define TPB  256
#define PPT  2              // points per thread (2 independent dep chains)
#define PPB  (TPB * PPT)    // 512 points per block
#define CHUNK 8             // boxes per load-batch (16 ds_read_b128 in flight)

// Single fused kernel. Each block:
//  1. stages its batch's raw boxes (896 f32, coalesced) into LDS,
//  2. threads 0..127 build the per-box record {cx,cy,cz,hx,hy,hz,cos,sin},
//  3. main loop: chunks of 8 boxes — load all 16 float4 into registers
//     (compile-time indices only), then compute. This batches LDS reads so
//     ds_read latency is paid once per chunk, not per box.
// Descending order overall: last write at smallest m == first containing box.
// __f*_rn blocks fp-contract so rounding matches np (mul, mul, add — no fma);
// this gave absmax = 0.0 in R1/R2.
__global__ __launch_bounds__(256) void pib_fused(const float* __restrict__ points,
                                                 const float* __restrict__ boxes,
                                                 float* __restrict__ out) {
    __shared__ float sraw[MBOX * 7];  // 3.5 KB raw boxes
    __shared__ float srec[MBOX * 8];  // 4.0 KB derived records

    const int blocksPerBatch = NPTS / PPB;            // 128
    int b   = blockIdx.x / blocksPerBatch;
    int blk = blockIdx.x % blocksPerBatch;

    // Issue point loads early (independent of LDS staging).
    size_t p0 = (size_t)b * NPTS + (size_t)blk * PPB + (size_t)threadIdx.x * PPT;
    const float* p = points + p0 * 3;                 // 24 B/thread, 8 B aligned
    float2 a01 = *(const float2*)(p);
    float2 a23 = *(const float2*)(p + 2);
    float2 a45 = *(const float2*)(p + 4);
    float px0 = a01.x, py0 = a01.y, pz0 = a23.x;
    float px1 = a23.y, py1 = a45.x, pz1 = a45.y;

    // Stage raw boxes, coalesced.
    const float* bsrc = boxes + (size_t)b * MBOX * 7;
    for (int i = threadIdx.x; i < MBOX * 7; i += TPB) sraw[i] = bsrc[i];
    __syncthreads();

    // Build derived records (one thread per box; stride-7 reads are
    // conflict-free since gcd(7,32)=1; one-time cost).
    if (threadIdx.x < MBOX) {
        const float* r = sraw + threadIdx.x * 7;
        float rz = r[6];
        float* o = srec + threadIdx.x * 8;
        o[0] = r[0]; o[1] = r[1]; o[2] = r[2];
        o[3] = 0.5f * r[3];   // exact, matches ref dims*0.5
        o[4] = 0.5f * r[4];
        o[5] = 0.5f * r[5];
        o[6] = cosf(rz);
        o[7] = sinf(rz);
    }
    __syncthreads();

    int idx0 = -1, idx1 = -1;
    for (int base = MBOX - CHUNK; base >= 0; base -= CHUNK) {
        // Batch-load the chunk's box records (uniform addr -> LDS broadcast).
        float4 q[2 * CHUNK];
        #pragma unroll
        for (int k = 0; k < CHUNK; ++k) {
            q[2 * k]     = ((const float4*)srec)[(base + k) * 2];
            q[2 * k + 1] = ((const float4*)srec)[(base + k) * 2 + 1];
        }
        // Compute, descending within chunk (keeps global descending order).
        #pragma unroll
        for (int k = CHUNK - 1; k >= 0; --k) {
            int m = base + k;
            float cx = q[2*k].x, cy = q[2*k].y, cz = q[2*k].z, hx = q[2*k].w;
            float hy = q[2*k+1].x, hz = q[2*k+1].y, cr = q[2*k+1].z, sr = q[2*k+1].w;

            // point 0
            float lx0 = __fsub_rn(px0, cx);
            float ly0 = __fsub_rn(py0, cy);
            float lz0 = __fsub_rn(pz0, cz);
            float X0 = __fadd_rn(__fmul_rn(lx0, cr), __fmul_rn(ly0, sr));
            float Y0 = __fadd_rn(__fmul_rn(-lx0, sr), __fmul_rn(ly0, cr));
            bool in0 = (fabsf(X0) <= hx) & (fabsf(Y0) <= hy) & (fabsf(lz0) <= hz);
            idx0 = in0 ? m : idx0;

            // point 1
            float lx1 = __fsub_rn(px1, cx);
            float ly1 = __fsub_rn(py1, cy);
            float lz1 = __fsub_rn(pz1, cz);
            float X1 = __fadd_rn(__fmul_rn(lx1, cr), __fmul_rn(ly1, sr));
            float Y1 = __fadd_rn(__fmul_rn(-lx1, sr), __fmul_rn(ly1, cr));
            bool in1 = (fabsf(X1) <= hx) & (fabsf(Y1) <= hy) & (fabsf(lz1) <= hz);
            idx1 = in1 ? m : idx1;
        }
    }

    // p0 is even -> 8 B aligned float2 store, coalesced.
    *(float2*)(out + p0) = make_float2((float)idx0, (float)idx1);
}

extern "C" void kernel_launch(void* const* d_in, const int* in_sizes, int n_in,
                              void* d_out, int out_size, void* d_ws, size_t ws_size,
                              hipStream_t stream) {
    const float* points = (const float*)d_in[0];   // [B, N, 3] f32
    const float* boxes  = (const float*)d_in[1];   // [B, M, 7] f32
    float* out = (float*)d_out;                    // [B, N]    f32

    int n_points = in_sizes[0] / 3;                // B*N = 262144
    int main_blocks = n_points / PPB;              // 512

    pib_fused<<<main_blocks, TPB, 0, stream>>>(points, boxes, out);
}